// Round 9
// baseline (548.389 us; speedup 1.0000x reference)
//
#include <hip/hip_runtime.h>

#define NB 8
#define NL 2048
#define ND 1024
#define NDI 2048
#define NDS 16
#define NDTR 64
#define NM (NB * NL)   // 16384 rows
#define CH 16          // scan chunks
#define CL (NL / CH)   // 128 per chunk

__device__ __forceinline__ float bf2f(unsigned int u) {
  union { unsigned int i; float f; } c; c.i = u << 16; return c.f;
}
__device__ __forceinline__ float lo16(unsigned int w) { return __uint_as_float(w << 16); }
__device__ __forceinline__ float hi16(unsigned int w) { return __uint_as_float(w & 0xffff0000u); }
__device__ __forceinline__ unsigned short f2bf(float f) {
  unsigned int x = __float_as_uint(f);
  x = x + 0x7fffu + ((x >> 16) & 1u);   // RNE (finite values only)
  return (unsigned short)(x >> 16);
}
__device__ __forceinline__ void dec8(int4 raw, float* f) {
  f[0] = lo16((unsigned)raw.x); f[1] = hi16((unsigned)raw.x);
  f[2] = lo16((unsigned)raw.y); f[3] = hi16((unsigned)raw.y);
  f[4] = lo16((unsigned)raw.z); f[5] = hi16((unsigned)raw.z);
  f[6] = lo16((unsigned)raw.w); f[7] = hi16((unsigned)raw.w);
}
// fast softplus: max(x,0) + log(1+exp(-|x|)), native exp/log only.
__device__ __forceinline__ float softplus_fast(float x) {
  return fmaxf(x, 0.f) + __logf(1.f + __expf(-fabsf(x)));
}

typedef __bf16 bf16x8 __attribute__((ext_vector_type(8)));
typedef float f32x4 __attribute__((ext_vector_type(4)));

__device__ __forceinline__ void gld_lds16(const unsigned short* g, unsigned short* l) {
  __builtin_amdgcn_global_load_lds(
      (const __attribute__((address_space(1))) unsigned int*)g,
      (__attribute__((address_space(3))) unsigned int*)l, 16, 0, 0);
}

// ---------------- LayerNorm: x (fp32) -> xn (bf16) ----------------
__global__ __launch_bounds__(256) void k_ln(const float* __restrict__ x,
    const float* __restrict__ lw, const float* __restrict__ lb,
    unsigned short* __restrict__ xn)
{
  const int row = blockIdx.x;
  const int tid = threadIdx.x;
  const float* xr = x + (size_t)row * ND;
  float4 v = reinterpret_cast<const float4*>(xr)[tid];
  float s  = v.x + v.y + v.z + v.w;
  float s2 = v.x*v.x + v.y*v.y + v.z*v.z + v.w*v.w;
  #pragma unroll
  for (int m = 32; m >= 1; m >>= 1) {
    s  += __shfl_xor(s, m);
    s2 += __shfl_xor(s2, m);
  }
  __shared__ float red[8];
  const int wid = tid >> 6;
  if ((tid & 63) == 0) { red[wid] = s; red[4 + wid] = s2; }
  __syncthreads();
  s  = red[0] + red[1] + red[2] + red[3];
  s2 = red[4] + red[5] + red[6] + red[7];
  const float mu   = s * (1.0f / ND);
  const float var  = s2 * (1.0f / ND) - mu * mu;
  const float rstd = rsqrtf(var + 1e-5f);
  const float4 wv = reinterpret_cast<const float4*>(lw)[tid];
  const float4 bv = reinterpret_cast<const float4*>(lb)[tid];
  ushort4 o;
  o.x = f2bf((v.x - mu) * rstd * wv.x + bv.x);
  o.y = f2bf((v.y - mu) * rstd * wv.y + bv.y);
  o.z = f2bf((v.z - mu) * rstd * wv.z + bv.z);
  o.w = f2bf((v.w - mu) * rstd * wv.w + bv.w);
  reinterpret_cast<ushort4*>(xn + (size_t)row * ND)[tid] = o;
}

// ---------------- weight prep: W (KxN fp32) -> WT (NxK bf16) ----------------
__global__ __launch_bounds__(256) void k_transpose(
    const float* __restrict__ W, unsigned short* __restrict__ WT,
    const int K, const int N)
{
  __shared__ float t[32][33];
  const int k0 = blockIdx.y * 32, n0 = blockIdx.x * 32;
  const int tx = threadIdx.x & 31, ty = threadIdx.x >> 5;
  #pragma unroll
  for (int r = 0; r < 4; ++r)
    t[ty + r * 8][tx] = W[(size_t)(k0 + ty + r * 8) * N + n0 + tx];
  __syncthreads();
  #pragma unroll
  for (int r = 0; r < 4; ++r)
    WT[(size_t)(n0 + ty + r * 8) * K + k0 + tx] = f2bf(t[tx][ty + r * 8]);
}

// ======== 8-phase 256x256 MFMA GEMM, BK=64, 8 waves, pipelined frags =======
// C = A(MxK bf16) * BT^T (BT is NxK bf16).  MODE 0: split bf16 store
// (col<NDI -> O0, else O1).  MODE 1: fp32 store acc + aux (residual).
// All 4 half-tile stages for tile t+1 issue during phases 1-2 of tile t
// (>=3-phase lead before the counted vmcnt that needs them).
// Ledger (per-thread instr): p1 +4 -> 8 out; p2 +4 -> 12, vmcnt(8) drains
// KH1(t); p4 vmcnt(4) drains KH0(t+1).  Buffers: stages target buf^1 only.
template<int MODE>
__global__ __launch_bounds__(512, 2) void k_mfma8(
    const unsigned short* __restrict__ A, const unsigned short* __restrict__ BT,
    const int K, const int N, void* __restrict__ O0, void* __restrict__ O1,
    const float* __restrict__ aux)
{
  __shared__ __align__(16) unsigned short sh[65536];   // 128 KiB
  const int tid = threadIdx.x, lane = tid & 63, wv = tid >> 6;
  const int wm = wv >> 2, wn = wv & 3;                 // 2 x 4 waves
  const int m16 = lane & 15, kb = lane >> 4;
  const int swzs = (((kb * 16) ^ (((m16 >> 1) & 3) << 4)) >> 1); // shorts
  const int arow = wm * 128 + m16;
  const int brow = wn * 64 + m16;

  // XCD-aware swizzle (grid %8 == 0 for both call sites)
  int wg = blockIdx.x;
  const int cpx = gridDim.x >> 3;
  wg = (wg & 7) * cpx + (wg >> 3);
  const int gnx = N >> 8;
  const int m0 = (wg / gnx) << 8;
  const int n0 = (wg % gnx) << 8;

  f32x4 acc[8][4];
  #pragma unroll
  for (int i = 0; i < 8; ++i)
    #pragma unroll
    for (int j = 0; j < 4; ++j)
      #pragma unroll
      for (int r = 0; r < 4; ++r) acc[i][j][r] = 0.f;

  auto STAGE = [&](const unsigned short* X, int x0, int kg, unsigned short* base) {
    #pragma unroll
    for (int jj = 0; jj < 2; ++jj) {
      const int s = (wv * 2 + jj) * 64 + lane;
      const int row = s >> 2;
      const int c = (lane & 3) ^ ((row >> 1) & 3);
      gld_lds16(X + (size_t)(x0 + row) * K + kg + c * 8, base + (wv * 2 + jj) * 512);
    }
  };
  auto RD_A = [&](bf16x8* dst, const unsigned short* base, int FH) {
    #pragma unroll
    for (int i = 0; i < 4; ++i)
      dst[i] = *reinterpret_cast<const bf16x8*>(base + (arow + FH * 64 + i * 16) * 32 + swzs);
  };
  auto RD_B = [&](bf16x8* dst, const unsigned short* base) {
    #pragma unroll
    for (int j = 0; j < 4; ++j)
      dst[j] = *reinterpret_cast<const bf16x8*>(base + (brow + j * 16) * 32 + swzs);
  };
  auto MM = [&](const bf16x8* aF, const bf16x8* bF, int off) {
    #pragma unroll
    for (int i = 0; i < 4; ++i)
      #pragma unroll
      for (int j = 0; j < 4; ++j)
        acc[off + i][j] = __builtin_amdgcn_mfma_f32_16x16x32_bf16(aF[i], bF[j], acc[off + i][j], 0, 0, 0);
  };

  // prologue: stage all 4 half-tiles of tile 0 into buf 0
  STAGE(A,  m0, 0,  sh);                       // A  k0
  STAGE(BT, n0, 0,  sh + 32768);               // B  k0
  STAGE(A,  m0, 32, sh + 8192);                // A  k1
  STAGE(BT, n0, 32, sh + 32768 + 8192);        // B  k1
  asm volatile("s_waitcnt vmcnt(0)" ::: "memory");
  __builtin_amdgcn_s_barrier();

  bf16x8 aA[4], aB[4], bA[4], bB[4];
  RD_A(aA, sh, 0);
  RD_B(bA, sh + 32768);

  const int NT = K >> 6;
  for (int t = 0; t < NT; ++t) {
    const int buf = t & 1, nb = buf ^ 1;
    const int kn = (t << 6) + 64;
    const bool more = (t + 1 < NT);
    const unsigned short* cA = sh + buf * 16384;
    const unsigned short* cB = sh + 32768 + buf * 16384;
    unsigned short* nA = sh + nb * 16384;
    unsigned short* nB = sh + 32768 + nb * 16384;

    // phase 1: MFMA(KH0,FH0)={aA,bA}; read aB=(KH0,FH1); stage A0,B0(t+1)
    if (more) { STAGE(A, m0, kn, nA); STAGE(BT, n0, kn, nB); }
    RD_A(aB, cA, 1);
    __builtin_amdgcn_sched_barrier(0);
    __builtin_amdgcn_s_setprio(1); MM(aA, bA, 0); __builtin_amdgcn_s_setprio(0);
    __builtin_amdgcn_s_barrier();

    // phase 2: MFMA(KH0,FH1)={aB,bA}; stage A1,B1(t+1); wait; read KH1 frags
    if (more) { STAGE(A, m0, kn + 32, nA + 8192); STAGE(BT, n0, kn + 32, nB + 8192); }
    if (more) { asm volatile("s_waitcnt vmcnt(8)" ::: "memory"); }
    else      { asm volatile("s_waitcnt vmcnt(0)" ::: "memory"); }
    __builtin_amdgcn_s_barrier();
    RD_A(aA, cA + 8192, 0);
    RD_B(bB, cB + 8192);
    __builtin_amdgcn_sched_barrier(0);
    __builtin_amdgcn_s_setprio(1); MM(aB, bA, 4); __builtin_amdgcn_s_setprio(0);
    __builtin_amdgcn_s_barrier();

    // phase 3: MFMA(KH1,FH0)={aA,bB}; read aB=(KH1,FH1)
    RD_A(aB, cA + 8192, 1);
    __builtin_amdgcn_sched_barrier(0);
    __builtin_amdgcn_s_setprio(1); MM(aA, bB, 0); __builtin_amdgcn_s_setprio(0);
    __builtin_amdgcn_s_barrier();

    // phase 4: MFMA(KH1,FH1)={aB,bB}; wait KH0(t+1); read next-tile KH0
    if (more) asm volatile("s_waitcnt vmcnt(4)" ::: "memory");
    __builtin_amdgcn_s_barrier();
    if (more) { RD_A(aA, nA, 0); RD_B(bA, nB); }
    __builtin_amdgcn_sched_barrier(0);
    __builtin_amdgcn_s_setprio(1); MM(aB, bB, 4); __builtin_amdgcn_s_setprio(0);
    __builtin_amdgcn_s_barrier();
  }

  // -------- LDS-transposed vectorized epilogue --------
  {
    float* fsh = (float*)sh;
    constexpr int LDP = 260;
    const int erow = tid >> 4;
    const int ec0  = tid & 15;
    const int growb = m0 + (erow >> 4) * 128 + (erow & 15);
    #pragma unroll
    for (int i = 0; i < 8; ++i) {
      __builtin_amdgcn_s_barrier();
      #pragma unroll
      for (int j = 0; j < 4; ++j)
        #pragma unroll
        for (int r = 0; r < 4; ++r)
          fsh[(wm * 16 + kb * 4 + r) * LDP + wn * 64 + j * 16 + m16] = acc[i][j][r];
      __builtin_amdgcn_s_barrier();
      const int grow = growb + i * 16;
      #pragma unroll
      for (int q = 0; q < 4; ++q) {
        const int c = (ec0 + q * 16) * 4;
        float4 v = *reinterpret_cast<const float4*>(&fsh[erow * LDP + c]);
        const int colg = n0 + c;
        if constexpr (MODE == 0) {
          ushort4 o = {f2bf(v.x), f2bf(v.y), f2bf(v.z), f2bf(v.w)};
          unsigned short* dst = (colg < NDI)
              ? (unsigned short*)O0 + (size_t)grow * NDI + colg
              : (unsigned short*)O1 + (size_t)grow * NDI + colg - NDI;
          *reinterpret_cast<ushort4*>(dst) = o;
        } else {
          float4 rv = *reinterpret_cast<const float4*>(aux + (size_t)grow * N + colg);
          float4 o = {v.x + rv.x, v.y + rv.y, v.z + rv.z, v.w + rv.w};
          *reinterpret_cast<float4*>((float*)O0 + (size_t)grow * N + colg) = o;
        }
      }
    }
  }
  (void)O1; (void)aux;
}

// ------- old 128x128 MFMA GEMM, kept for dt-proj (K=64, softplus epilogue) --
__global__ __launch_bounds__(256) void k_mfma_dt(
    const unsigned short* __restrict__ A, const unsigned short* __restrict__ BT,
    const int K, void* __restrict__ O0, const float* __restrict__ aux, const int N)
{
  __shared__ __align__(16) unsigned short As[128 * 32];
  __shared__ __align__(16) unsigned short Bs[128 * 32];
  const int tid = threadIdx.x;
  const int lane = tid & 63;
  const int wv = tid >> 6;
  const int wm = wv >> 1, wn = wv & 1;
  const int m0 = blockIdx.y * 128, n0 = blockIdx.x * 128;
  const int m16 = lane & 15, kb = lane >> 4;
  const int wbase = wv * 64;

  f32x4 acc[4][4];
  #pragma unroll
  for (int i = 0; i < 4; ++i)
    #pragma unroll
    for (int j = 0; j < 4; ++j)
      #pragma unroll
      for (int r = 0; r < 4; ++r) acc[i][j][r] = 0.f;

  for (int k0 = 0; k0 < K; k0 += 32) {
    #pragma unroll
    for (int it = 0; it < 2; ++it) {
      const int c = it * 256 + tid;
      const int r = c >> 2, cb = c & 3;
      gld_lds16(A  + (size_t)(m0 + r) * K + k0 + cb * 8, As + (size_t)(it * 256 + wbase) * 8);
      gld_lds16(BT + (size_t)(n0 + r) * K + k0 + cb * 8, Bs + (size_t)(it * 256 + wbase) * 8);
    }
    __syncthreads();
    bf16x8 af[4], bfr[4];
    #pragma unroll
    for (int i = 0; i < 4; ++i)
      af[i] = *reinterpret_cast<const bf16x8*>(&As[(wm * 64 + i * 16 + m16) * 32 + kb * 8]);
    #pragma unroll
    for (int j = 0; j < 4; ++j)
      bfr[j] = *reinterpret_cast<const bf16x8*>(&Bs[(wn * 64 + j * 16 + m16) * 32 + kb * 8]);
    #pragma unroll
    for (int i = 0; i < 4; ++i)
      #pragma unroll
      for (int j = 0; j < 4; ++j)
        acc[i][j] = __builtin_amdgcn_mfma_f32_16x16x32_bf16(af[i], bfr[j], acc[i][j], 0, 0, 0);
    __syncthreads();
  }

  const int r0 = (lane >> 4) * 4;
  #pragma unroll
  for (int i = 0; i < 4; ++i) {
    const int rowb = m0 + wm * 64 + i * 16 + r0;
    #pragma unroll
    for (int j = 0; j < 4; ++j) {
      const int col = n0 + wn * 64 + j * 16 + m16;
      #pragma unroll
      for (int r = 0; r < 4; ++r) {
        const int row = rowb + r;
        ((unsigned short*)O0)[(size_t)row * N + col] =
            f2bf(softplus_fast(acc[i][j][r] + aux[col]));
      }
    }
  }
}

// ------- depthwise causal conv (K=4) + bias + SiLU, sliding window ----------
__global__ __launch_bounds__(256) void k_conv(
    const unsigned short* __restrict__ up, const float* __restrict__ cw,
    const float* __restrict__ cb, unsigned short* __restrict__ u)
{
  const int tid = threadIdx.x;
  const int c0 = tid * 8;
  const int lt = blockIdx.x & 127;       // NL/16 tiles
  const int b  = blockIdx.x >> 7;
  const int l0 = lt * 16;

  float4 wv[8];
  #pragma unroll
  for (int j = 0; j < 8; ++j)
    wv[j] = reinterpret_cast<const float4*>(cw + (size_t)c0 * 4)[j];
  float bias[8];
  {
    float4 b0 = reinterpret_cast<const float4*>(cb + c0)[0];
    float4 b1 = reinterpret_cast<const float4*>(cb + c0)[1];
    bias[0]=b0.x; bias[1]=b0.y; bias[2]=b0.z; bias[3]=b0.w;
    bias[4]=b1.x; bias[5]=b1.y; bias[6]=b1.z; bias[7]=b1.w;
  }

  const size_t base = ((size_t)b * NL + l0) * NDI + c0;
  float w0[8], w1[8], w2[8];   // rows l0-3, l0-2, l0-1
  if (l0 >= 3) {
    int4 r0 = *reinterpret_cast<const int4*>(up + base - 3 * NDI);
    int4 r1 = *reinterpret_cast<const int4*>(up + base - 2 * NDI);
    int4 r2 = *reinterpret_cast<const int4*>(up + base - 1 * NDI);
    dec8(r0, w0); dec8(r1, w1); dec8(r2, w2);
  } else {
    #pragma unroll
    for (int j = 0; j < 8; ++j) { w0[j] = 0.f; w1[j] = 0.f; w2[j] = 0.f; }
  }

  #pragma unroll
  for (int l = 0; l < 16; ++l) {
    int4 raw = *reinterpret_cast<const int4*>(up + base + (size_t)l * NDI);
    float cur[8];
    dec8(raw, cur);
    unsigned short o[8];
    #pragma unroll
    for (int j = 0; j < 8; ++j) {
      const float a = bias[j] + wv[j].x * w0[j] + wv[j].y * w1[j]
                              + wv[j].z * w2[j] + wv[j].w * cur[j];
      o[j] = f2bf(a / (1.f + __expf(-a)));
    }
    ushort4 o0 = {o[0], o[1], o[2], o[3]};
    ushort4 o1 = {o[4], o[5], o[6], o[7]};
    unsigned short* dst = u + base + (size_t)l * NDI;
    *reinterpret_cast<ushort4*>(dst)     = o0;
    *reinterpret_cast<ushort4*>(dst + 4) = o1;
    #pragma unroll
    for (int j = 0; j < 8; ++j) { w0[j] = w1[j]; w1[j] = w2[j]; w2[j] = cur[j]; }
  }
}

// ---------------- xd projection (MFMA): u(16384x2048 bf16) @ WxT^T(96x2048) --
// 64-row tiles (grid 256 = full GPU), 4 waves, XOR-swizzled LDS (2-way free),
// double-buffered global_load_lds staging.
// cols 0..63 -> xdt bf16 [row][64]; 64..79 -> xb f32; 80..95 -> xc f32
__global__ __launch_bounds__(256) void k_xd_mfma(
    const unsigned short* __restrict__ A, const unsigned short* __restrict__ BT,
    unsigned short* __restrict__ xdt, float* __restrict__ xb,
    float* __restrict__ xc)
{
  __shared__ __align__(16) unsigned short As[2][64 * 32];
  __shared__ __align__(16) unsigned short Bs[2][96 * 32];
  const int tid = threadIdx.x, lane = tid & 63, wvv = tid >> 6;  // 4 waves
  const int m0 = blockIdx.x * 64;
  const int m16 = lane & 15, kb = lane >> 4;
  const int sw = (kb ^ ((m16 >> 1) & 3)) * 8;   // swizzled k-offset (shorts)

  f32x4 acc[6];
  #pragma unroll
  for (int j = 0; j < 6; ++j)
    #pragma unroll
    for (int r = 0; r < 4; ++r) acc[j][r] = 0.f;

  auto STG = [&](int bb, int kg) {
    {
      const int row = tid >> 2, c = tid & 3;
      const int sc = c ^ ((row >> 1) & 3);
      gld_lds16(A + (size_t)(m0 + row) * NDI + kg + sc * 8, &As[bb][tid * 8]);
      gld_lds16(BT + (size_t)row * NDI + kg + sc * 8, &Bs[bb][tid * 8]);
    }
    if (tid < 128) {
      const int s = 256 + tid;
      const int row = s >> 2, c = s & 3;
      const int sc = c ^ ((row >> 1) & 3);
      gld_lds16(BT + (size_t)row * NDI + kg + sc * 8, &Bs[bb][s * 8]);
    }
  };

  STG(0, 0);
  asm volatile("s_waitcnt vmcnt(0)" ::: "memory");
  __syncthreads();

  for (int t = 0; t < NDI / 32; ++t) {
    const int cur = t & 1;
    if (t + 1 < NDI / 32) STG(cur ^ 1, (t + 1) * 32);
    bf16x8 af = *reinterpret_cast<const bf16x8*>(&As[cur][(wvv * 16 + m16) * 32 + sw]);
    bf16x8 bfr[6];
    #pragma unroll
    for (int j = 0; j < 6; ++j)
      bfr[j] = *reinterpret_cast<const bf16x8*>(&Bs[cur][(j * 16 + m16) * 32 + sw]);
    #pragma unroll
    for (int j = 0; j < 6; ++j)
      acc[j] = __builtin_amdgcn_mfma_f32_16x16x32_bf16(af, bfr[j], acc[j], 0, 0, 0);
    asm volatile("s_waitcnt vmcnt(0)" ::: "memory");
    __syncthreads();
  }

  const int r0 = kb * 4;
  #pragma unroll
  for (int j = 0; j < 6; ++j) {
    const int col = j * 16 + m16;
    #pragma unroll
    for (int r = 0; r < 4; ++r) {
      const int row = m0 + wvv * 16 + r0 + r;
      const float v = acc[j][r];
      if (j < 4)       xdt[(size_t)row * 64 + col] = f2bf(v);
      else if (j == 4) xb[(size_t)row * 16 + col - 64] = v;
      else             xc[(size_t)row * 16 + col - 80] = v;
    }
  }
}

// ---------------- chunked selective scan, lane-per-channel ----------------
// PHASE 0: local scan -> HF[b][c][d][s] final state, Sdt[b][c][d] = sum(dt)
// PHASE 1: scan from corrected init (in HF); y = (h.C + u*D)*silu(z) over u_io
// Fast path (input-structure detected at runtime, __all-uniform): when
// Ac[s] == Ac[0]*(s+1) (A_log = log(arange(1..NDS)) broadcast), dA_s = q^(s+1)
// with q = exp(dt*Ac[0]) -> 1 exp + 15 mul instead of 16 exp.
template<int PHASE>
__global__ __launch_bounds__(256) void k_scan3(
    const unsigned short* __restrict__ dt, unsigned short* __restrict__ u_io,
    const unsigned short* __restrict__ z,
    const float* __restrict__ xb, const float* __restrict__ xc,
    const float* __restrict__ A_log, const float* __restrict__ Dp,
    float* __restrict__ HF, float* __restrict__ Sdt)
{
  const int tid = threadIdx.x;
  const int blk = blockIdx.x;
  const int b = blk >> 7;
  const int c = (blk >> 3) & (CH - 1);
  if (PHASE == 0 && c == CH - 1) return;   // last chunk's carry unused
  const int d = (blk & 7) * 256 + tid;

  __shared__ float Bsl[CL][16];
  __shared__ float Csl[(PHASE == 1) ? CL : 1][16];
  const size_t rbase = (size_t)b * NL + (size_t)c * CL;
  #pragma unroll
  for (int i = 0; i < 2; ++i) {
    const int idx = i * 256 + tid;       // 0..511  (CL*16/4 = 512 float4)
    const int r = idx >> 2, q = idx & 3;
    reinterpret_cast<float4*>(&Bsl[r][q * 4])[0] =
        reinterpret_cast<const float4*>(xb + (rbase + r) * 16)[q];
    if constexpr (PHASE == 1)
      reinterpret_cast<float4*>(&Csl[r][q * 4])[0] =
          reinterpret_cast<const float4*>(xc + (rbase + r) * 16)[q];
  }
  __syncthreads();

  float Ac[16];
  #pragma unroll
  for (int q = 0; q < 4; ++q) {
    float4 a = reinterpret_cast<const float4*>(A_log + (size_t)d * 16)[q];
    Ac[q*4+0] = -__expf(a.x); Ac[q*4+1] = -__expf(a.y);
    Ac[q*4+2] = -__expf(a.z); Ac[q*4+3] = -__expf(a.w);
  }
  bool fastok = true;
  #pragma unroll
  for (int s = 1; s < 16; ++s)
    fastok = fastok && (fabsf(Ac[s] - Ac[0] * (float)(s + 1)) <= 1e-5f * fabsf(Ac[s]));
  const bool fast = __all(fastok);

  const size_t hoff = ((size_t)(b * CH + c) * NDI + d) * 16;
  float h[16];
  if constexpr (PHASE == 0) {
    #pragma unroll
    for (int s = 0; s < 16; ++s) h[s] = 0.f;
  } else {
    #pragma unroll
    for (int q = 0; q < 4; ++q) {
      float4 hv = reinterpret_cast<const float4*>(HF + hoff)[q];
      h[q*4+0] = hv.x; h[q*4+1] = hv.y; h[q*4+2] = hv.z; h[q*4+3] = hv.w;
    }
  }
  const float Dd = Dp[d];
  const float Ac0 = Ac[0];
  float sdt = 0.f;
  size_t idx = rbase * NDI + d;

  if (fast) {
    for (int l = 0; l < CL; ++l, idx += NDI) {
      const float dtv = bf2f(dt[idx]);
      const float uv  = bf2f(u_io[idx]);
      const float dtu = dtv * uv;
      const float qq = __expf(dtv * Ac0);
      float e = qq;
      if constexpr (PHASE == 0) {
        sdt += dtv;
        #pragma unroll
        for (int s = 0; s < 16; ++s) {
          h[s] = h[s] * e + dtu * Bsl[l][s];
          e *= qq;
        }
      } else {
        float yp = 0.f;
        #pragma unroll
        for (int s = 0; s < 16; ++s) {
          h[s] = h[s] * e + dtu * Bsl[l][s];
          yp += h[s] * Csl[l][s];
          e *= qq;
        }
        const float zv = bf2f(z[idx]);
        const float sil = zv / (1.f + __expf(-zv));
        u_io[idx] = f2bf((yp + uv * Dd) * sil);
      }
    }
  } else {
    for (int l = 0; l < CL; ++l, idx += NDI) {
      const float dtv = bf2f(dt[idx]);
      const float uv  = bf2f(u_io[idx]);
      const float dtu = dtv * uv;
      if constexpr (PHASE == 0) {
        sdt += dtv;
        #pragma unroll
        for (int s = 0; s < 16; ++s) {
          const float e = __expf(dtv * Ac[s]);
          h[s] = h[s] * e + dtu * Bsl[l][s];
        }
      } else {
        float yp = 0.f;
        #pragma unroll
        for (int s = 0; s < 16; ++s) {
          const float e = __expf(dtv * Ac[s]);
          h[s] = h[s] * e + dtu * Bsl[l][s];
          yp += h[s] * Csl[l][s];
        }
        const float zv = bf2f(z[idx]);
        const float sil = zv / (1.f + __expf(-zv));
        u_io[idx] = f2bf((yp + uv * Dd) * sil);
      }
    }
  }

  if constexpr (PHASE == 0) {
    #pragma unroll
    for (int q = 0; q < 4; ++q) {
      float4 hv = {h[q*4+0], h[q*4+1], h[q*4+2], h[q*4+3]};
      reinterpret_cast<float4*>(HF + hoff)[q] = hv;
    }
    Sdt[(size_t)(b * CH + c) * NDI + d] = sdt;
  }
}

// serial combine over chunks: HF[b][c][d][s] <- init state of chunk c
__global__ __launch_bounds__(256) void k_comb(
    float* __restrict__ HF, const float* __restrict__ Sdt,
    const float* __restrict__ A_log)
{
  const int t = blockIdx.x * 256 + threadIdx.x;   // b*32768 + d*16 + s
  const int b = t >> 15;
  const int q = t & 32767;
  const int d = q >> 4;
  const float Ac = -__expf(A_log[q]);
  float H = 0.f;
  #pragma unroll
  for (int c = 0; c < CH; ++c) {
    const size_t off = (((size_t)(b * CH + c) * NDI) << 4) + q;
    const float hf = HF[off];
    const float p  = __expf(Ac * Sdt[(size_t)(b * CH + c) * NDI + d]);
    HF[off] = H;
    H = p * H + hf;
  }
}

extern "C" void kernel_launch(void* const* d_in, const int* in_sizes, int n_in,
                              void* d_out, int out_size, void* d_ws, size_t ws_size,
                              hipStream_t stream) {
  (void)in_sizes; (void)n_in; (void)out_size; (void)ws_size;
  const float* x      = (const float*)d_in[0];
  const float* ln_w   = (const float*)d_in[1];
  const float* ln_b   = (const float*)d_in[2];
  const float* W_in   = (const float*)d_in[3];
  const float* conv_w = (const float*)d_in[4];
  const float* conv_b = (const float*)d_in[5];
  const float* W_x    = (const float*)d_in[6];
  const float* W_dt   = (const float*)d_in[7];
  const float* b_dt   = (const float*)d_in[8];
  const float* A_log  = (const float*)d_in[9];
  const float* Dp     = (const float*)d_in[10];
  const float* W_out  = (const float*)d_in[11];
  float* out = (float*)d_out;

  char* ws = (char*)d_ws;
  // 0..32M: xn (bf16, dead after GEMM1) -> HF (f32, scan)
  unsigned short* xn   = (unsigned short*)(ws);
  float*          HF   = (float*)(ws);
  unsigned short* upre = (unsigned short*)(ws + 33554432);   // 64M: u-pre / dt
  unsigned short* zbuf = (unsigned short*)(ws + 100663296);  // 64M
  unsigned short* ubuf = (unsigned short*)(ws + 167772160);  // 64M: u / y
  unsigned short* xdt  = (unsigned short*)(ws + 234881024);  // 2M (dead after dt-proj) -> Sdt
  float*          Sdt  = (float*)(ws + 234881024);           // 2M
  float*          xb   = (float*)(ws + 236978176);           // 1M
  float*          xc   = (float*)(ws + 238026752);           // 1M
  unsigned short* WxT  = (unsigned short*)(ws + 239075328);  // 384K
  unsigned short* WdtT = (unsigned short*)(ws + 239468544);  // 256K
  unsigned short* WinT = (unsigned short*)(ws + 240123904);  // 8M
  unsigned short* WoutT= (unsigned short*)(ws + 248512512);  // 4M -> ends 252706816

  // weight prep
  dim3 gt1(4096 / 32, 1024 / 32);
  k_transpose<<<gt1, 256, 0, stream>>>(W_in, WinT, 1024, 4096);
  dim3 gt2(1024 / 32, 2048 / 32);
  k_transpose<<<gt2, 256, 0, stream>>>(W_out, WoutT, 2048, 1024);
  dim3 gt3(96 / 32, 2048 / 32);
  k_transpose<<<gt3, 256, 0, stream>>>(W_x, WxT, 2048, 96);
  dim3 gt4(2048 / 32, 64 / 32);
  k_transpose<<<gt4, 256, 0, stream>>>(W_dt, WdtT, 64, 2048);

  k_ln<<<NM, 256, 0, stream>>>(x, ln_w, ln_b, xn);

  // GEMM1: 16384x4096x1024, 8-phase 256^2
  k_mfma8<0><<<(NM / 256) * (4096 / 256), 512, 0, stream>>>(
      xn, WinT, 1024, 4096, upre, zbuf, nullptr);

  k_conv<<<NB * (NL / 16), 256, 0, stream>>>(upre, conv_w, conv_b, ubuf);

  k_xd_mfma<<<NM / 64, 256, 0, stream>>>(ubuf, WxT, xdt, xb, xc);

  dim3 g3(2048 / 128, NM / 128);
  k_mfma_dt<<<g3, 256, 0, stream>>>(xdt, WdtT, 64, upre, b_dt, 2048);

  const int nscan = NB * CH * (NDI / 256);   // 1024 blocks
  k_scan3<0><<<nscan, 256, 0, stream>>>(upre, ubuf, zbuf, xb, xc, A_log, Dp, HF, Sdt);
  k_comb<<<NB * NDI * NDS / 256, 256, 0, stream>>>(HF, Sdt, A_log);
  k_scan3<1><<<nscan, 256, 0, stream>>>(upre, ubuf, zbuf, xb, xc, A_log, Dp, HF, Sdt);

  // GEMM4: 16384x1024x2048, 8-phase 256^2, +residual
  k_mfma8<1><<<(NM / 256) * (1024 / 256), 512, 0, stream>>>(
      ubuf, WoutT, 2048, 1024, out, nullptr, x);
}

// Round 10
// 540.775 us; speedup vs baseline: 1.0141x; 1.0141x over previous
//
#include <hip/hip_runtime.h>

#define NB 8
#define NL 2048
#define ND 1024
#define NDI 2048
#define NDS 16
#define NDTR 64
#define NM (NB * NL)   // 16384 rows
#define CH 16          // scan chunks
#define CL (NL / CH)   // 128 per chunk

__device__ __forceinline__ float bf2f(unsigned int u) {
  union { unsigned int i; float f; } c; c.i = u << 16; return c.f;
}
__device__ __forceinline__ float lo16(unsigned int w) { return __uint_as_float(w << 16); }
__device__ __forceinline__ float hi16(unsigned int w) { return __uint_as_float(w & 0xffff0000u); }
__device__ __forceinline__ unsigned short f2bf(float f) {
  unsigned int x = __float_as_uint(f);
  x = x + 0x7fffu + ((x >> 16) & 1u);   // RNE (finite values only)
  return (unsigned short)(x >> 16);
}
__device__ __forceinline__ void dec8(int4 raw, float* f) {
  f[0] = lo16((unsigned)raw.x); f[1] = hi16((unsigned)raw.x);
  f[2] = lo16((unsigned)raw.y); f[3] = hi16((unsigned)raw.y);
  f[4] = lo16((unsigned)raw.z); f[5] = hi16((unsigned)raw.z);
  f[6] = lo16((unsigned)raw.w); f[7] = hi16((unsigned)raw.w);
}
// fast softplus: max(x,0) + log(1+exp(-|x|)), native exp/log only.
__device__ __forceinline__ float softplus_fast(float x) {
  return fmaxf(x, 0.f) + __logf(1.f + __expf(-fabsf(x)));
}

typedef __bf16 bf16x8 __attribute__((ext_vector_type(8)));
typedef float f32x4 __attribute__((ext_vector_type(4)));

__device__ __forceinline__ void gld_lds16(const unsigned short* g, unsigned short* l) {
  __builtin_amdgcn_global_load_lds(
      (const __attribute__((address_space(1))) unsigned int*)g,
      (__attribute__((address_space(3))) unsigned int*)l, 16, 0, 0);
}

// ---------------- LayerNorm: x (fp32) -> xn (bf16) ----------------
__global__ __launch_bounds__(256) void k_ln(const float* __restrict__ x,
    const float* __restrict__ lw, const float* __restrict__ lb,
    unsigned short* __restrict__ xn)
{
  const int row = blockIdx.x;
  const int tid = threadIdx.x;
  const float* xr = x + (size_t)row * ND;
  float4 v = reinterpret_cast<const float4*>(xr)[tid];
  float s  = v.x + v.y + v.z + v.w;
  float s2 = v.x*v.x + v.y*v.y + v.z*v.z + v.w*v.w;
  #pragma unroll
  for (int m = 32; m >= 1; m >>= 1) {
    s  += __shfl_xor(s, m);
    s2 += __shfl_xor(s2, m);
  }
  __shared__ float red[8];
  const int wid = tid >> 6;
  if ((tid & 63) == 0) { red[wid] = s; red[4 + wid] = s2; }
  __syncthreads();
  s  = red[0] + red[1] + red[2] + red[3];
  s2 = red[4] + red[5] + red[6] + red[7];
  const float mu   = s * (1.0f / ND);
  const float var  = s2 * (1.0f / ND) - mu * mu;
  const float rstd = rsqrtf(var + 1e-5f);
  const float4 wv = reinterpret_cast<const float4*>(lw)[tid];
  const float4 bv = reinterpret_cast<const float4*>(lb)[tid];
  ushort4 o;
  o.x = f2bf((v.x - mu) * rstd * wv.x + bv.x);
  o.y = f2bf((v.y - mu) * rstd * wv.y + bv.y);
  o.z = f2bf((v.z - mu) * rstd * wv.z + bv.z);
  o.w = f2bf((v.w - mu) * rstd * wv.w + bv.w);
  reinterpret_cast<ushort4*>(xn + (size_t)row * ND)[tid] = o;
}

// ---------------- weight prep: W (KxN fp32) -> WT (NxK bf16) ----------------
__global__ __launch_bounds__(256) void k_transpose(
    const float* __restrict__ W, unsigned short* __restrict__ WT,
    const int K, const int N)
{
  __shared__ float t[32][33];
  const int k0 = blockIdx.y * 32, n0 = blockIdx.x * 32;
  const int tx = threadIdx.x & 31, ty = threadIdx.x >> 5;
  #pragma unroll
  for (int r = 0; r < 4; ++r)
    t[ty + r * 8][tx] = W[(size_t)(k0 + ty + r * 8) * N + n0 + tx];
  __syncthreads();
  #pragma unroll
  for (int r = 0; r < 4; ++r)
    WT[(size_t)(n0 + ty + r * 8) * K + k0 + tx] = f2bf(t[tx][ty + r * 8]);
}

// ===== 2-phase 256x256 MFMA GEMM, BK=32, 64KiB LDS -> 2 blocks/CU =========
// C = A(MxK bf16) * BT^T (BT is NxK bf16).  MODE 0: split bf16 store
// (col<NDI -> O0, else O1).  MODE 1: fp32 store acc + aux (residual).
// Minimal double-buffered template (T3 recipe): per K-tile(32):
//   STAGE(next tile -> buf^1); read 12 frags; 32 MFMA; vmcnt(0); barrier.
// One barrier + one drain per tile (4x fewer than the 8-phase variant);
// 64KiB LDS gives 2 co-resident blocks/CU so drains overlap the other
// block's MFMA (m114 wave-level-overlap mechanism).
// Race safety: prior-tile ds_reads retire before their consuming MFMA
// (compiler lgkmcnt), hence before the barrier; post-barrier stages into
// that buffer are safe.  vmcnt(0)+barrier publishes staged data.
template<int MODE>
__global__ __launch_bounds__(512, 2) void k_mfma2(
    const unsigned short* __restrict__ A, const unsigned short* __restrict__ BT,
    const int K, const int N, void* __restrict__ O0, void* __restrict__ O1,
    const float* __restrict__ aux)
{
  __shared__ __align__(16) unsigned short sh[32768];   // 64 KiB: [2][A 16KB|B 16KB]
  const int tid = threadIdx.x, lane = tid & 63, wv = tid >> 6;
  const int wm = wv >> 2, wn = wv & 3;                 // 2 x 4 waves
  const int m16 = lane & 15, kb = lane >> 4;
  const int swzs = (((kb * 16) ^ (((m16 >> 1) & 3) << 4)) >> 1); // shorts
  const int arow = wm * 128 + m16;
  const int brow = wn * 64 + m16;

  // XCD-aware swizzle (grid %8 == 0 for both call sites)
  int wg = blockIdx.x;
  const int cpx = gridDim.x >> 3;
  wg = (wg & 7) * cpx + (wg >> 3);
  const int gnx = N >> 8;
  const int m0 = (wg / gnx) << 8;
  const int n0 = (wg % gnx) << 8;

  f32x4 acc[8][4];
  #pragma unroll
  for (int i = 0; i < 8; ++i)
    #pragma unroll
    for (int j = 0; j < 4; ++j)
      #pragma unroll
      for (int r = 0; r < 4; ++r) acc[i][j][r] = 0.f;

  // stage one 256x32 bf16 tile (16KB) = 2 gld_lds16 per thread
  auto STAGE = [&](const unsigned short* X, int x0, int kg, unsigned short* base) {
    #pragma unroll
    for (int jj = 0; jj < 2; ++jj) {
      const int s = (wv * 2 + jj) * 64 + lane;
      const int row = s >> 2;
      const int c = (lane & 3) ^ ((row >> 1) & 3);
      gld_lds16(X + (size_t)(x0 + row) * K + kg + c * 8, base + (wv * 2 + jj) * 512);
    }
  };
  auto RD_A = [&](bf16x8* dst, const unsigned short* base, int FH) {
    #pragma unroll
    for (int i = 0; i < 4; ++i)
      dst[i] = *reinterpret_cast<const bf16x8*>(base + (arow + FH * 64 + i * 16) * 32 + swzs);
  };
  auto RD_B = [&](bf16x8* dst, const unsigned short* base) {
    #pragma unroll
    for (int j = 0; j < 4; ++j)
      dst[j] = *reinterpret_cast<const bf16x8*>(base + (brow + j * 16) * 32 + swzs);
  };
  auto MM = [&](const bf16x8* aF, const bf16x8* bF, int off) {
    #pragma unroll
    for (int i = 0; i < 4; ++i)
      #pragma unroll
      for (int j = 0; j < 4; ++j)
        acc[off + i][j] = __builtin_amdgcn_mfma_f32_16x16x32_bf16(aF[i], bF[j], acc[off + i][j], 0, 0, 0);
  };

  // prologue: stage tile 0 into buf 0
  STAGE(A,  m0, 0, sh);
  STAGE(BT, n0, 0, sh + 8192);
  asm volatile("s_waitcnt vmcnt(0)" ::: "memory");
  __builtin_amdgcn_s_barrier();

  const int NT = K >> 5;
  for (int t = 0; t < NT; ++t) {
    const int buf = t & 1;
    const unsigned short* cA = sh + buf * 16384;
    const unsigned short* cB = cA + 8192;
    unsigned short* nA = sh + (buf ^ 1) * 16384;
    const bool more = (t + 1 < NT);
    if (more) {
      const int kn = (t + 1) << 5;
      STAGE(A,  m0, kn, nA);
      STAGE(BT, n0, kn, nA + 8192);
    }
    bf16x8 a0[4], a1[4], bF[4];
    RD_A(a0, cA, 0);
    RD_B(bF, cB);
    RD_A(a1, cA, 1);
    __builtin_amdgcn_sched_barrier(0);
    __builtin_amdgcn_s_setprio(1);
    MM(a0, bF, 0);
    MM(a1, bF, 4);
    __builtin_amdgcn_s_setprio(0);
    if (more) asm volatile("s_waitcnt vmcnt(0)" ::: "memory");
    __builtin_amdgcn_s_barrier();
  }

  // -------- LDS-transposed vectorized epilogue (33KB < 64KB) --------
  {
    float* fsh = (float*)sh;
    constexpr int LDP = 260;
    const int erow = tid >> 4;
    const int ec0  = tid & 15;
    const int growb = m0 + (erow >> 4) * 128 + (erow & 15);
    #pragma unroll
    for (int i = 0; i < 8; ++i) {
      __builtin_amdgcn_s_barrier();
      #pragma unroll
      for (int j = 0; j < 4; ++j)
        #pragma unroll
        for (int r = 0; r < 4; ++r)
          fsh[(wm * 16 + kb * 4 + r) * LDP + wn * 64 + j * 16 + m16] = acc[i][j][r];
      __builtin_amdgcn_s_barrier();
      const int grow = growb + i * 16;
      #pragma unroll
      for (int q = 0; q < 4; ++q) {
        const int c = (ec0 + q * 16) * 4;
        float4 v = *reinterpret_cast<const float4*>(&fsh[erow * LDP + c]);
        const int colg = n0 + c;
        if constexpr (MODE == 0) {
          ushort4 o = {f2bf(v.x), f2bf(v.y), f2bf(v.z), f2bf(v.w)};
          unsigned short* dst = (colg < NDI)
              ? (unsigned short*)O0 + (size_t)grow * NDI + colg
              : (unsigned short*)O1 + (size_t)grow * NDI + colg - NDI;
          *reinterpret_cast<ushort4*>(dst) = o;
        } else {
          float4 rv = *reinterpret_cast<const float4*>(aux + (size_t)grow * N + colg);
          float4 o = {v.x + rv.x, v.y + rv.y, v.z + rv.z, v.w + rv.w};
          *reinterpret_cast<float4*>((float*)O0 + (size_t)grow * N + colg) = o;
        }
      }
    }
  }
  (void)O1; (void)aux;
}

// ------- old 128x128 MFMA GEMM, kept for dt-proj (K=64, softplus epilogue) --
__global__ __launch_bounds__(256) void k_mfma_dt(
    const unsigned short* __restrict__ A, const unsigned short* __restrict__ BT,
    const int K, void* __restrict__ O0, const float* __restrict__ aux, const int N)
{
  __shared__ __align__(16) unsigned short As[128 * 32];
  __shared__ __align__(16) unsigned short Bs[128 * 32];
  const int tid = threadIdx.x;
  const int lane = tid & 63;
  const int wv = tid >> 6;
  const int wm = wv >> 1, wn = wv & 1;
  const int m0 = blockIdx.y * 128, n0 = blockIdx.x * 128;
  const int m16 = lane & 15, kb = lane >> 4;
  const int wbase = wv * 64;

  f32x4 acc[4][4];
  #pragma unroll
  for (int i = 0; i < 4; ++i)
    #pragma unroll
    for (int j = 0; j < 4; ++j)
      #pragma unroll
      for (int r = 0; r < 4; ++r) acc[i][j][r] = 0.f;

  for (int k0 = 0; k0 < K; k0 += 32) {
    #pragma unroll
    for (int it = 0; it < 2; ++it) {
      const int c = it * 256 + tid;
      const int r = c >> 2, cb = c & 3;
      gld_lds16(A  + (size_t)(m0 + r) * K + k0 + cb * 8, As + (size_t)(it * 256 + wbase) * 8);
      gld_lds16(BT + (size_t)(n0 + r) * K + k0 + cb * 8, Bs + (size_t)(it * 256 + wbase) * 8);
    }
    __syncthreads();
    bf16x8 af[4], bfr[4];
    #pragma unroll
    for (int i = 0; i < 4; ++i)
      af[i] = *reinterpret_cast<const bf16x8*>(&As[(wm * 64 + i * 16 + m16) * 32 + kb * 8]);
    #pragma unroll
    for (int j = 0; j < 4; ++j)
      bfr[j] = *reinterpret_cast<const bf16x8*>(&Bs[(wn * 64 + j * 16 + m16) * 32 + kb * 8]);
    #pragma unroll
    for (int i = 0; i < 4; ++i)
      #pragma unroll
      for (int j = 0; j < 4; ++j)
        acc[i][j] = __builtin_amdgcn_mfma_f32_16x16x32_bf16(af[i], bfr[j], acc[i][j], 0, 0, 0);
    __syncthreads();
  }

  const int r0 = (lane >> 4) * 4;
  #pragma unroll
  for (int i = 0; i < 4; ++i) {
    const int rowb = m0 + wm * 64 + i * 16 + r0;
    #pragma unroll
    for (int j = 0; j < 4; ++j) {
      const int col = n0 + wn * 64 + j * 16 + m16;
      #pragma unroll
      for (int r = 0; r < 4; ++r) {
        const int row = rowb + r;
        ((unsigned short*)O0)[(size_t)row * N + col] =
            f2bf(softplus_fast(acc[i][j][r] + aux[col]));
      }
    }
  }
}

// ------- depthwise causal conv (K=4) + bias + SiLU, sliding window ----------
__global__ __launch_bounds__(256) void k_conv(
    const unsigned short* __restrict__ up, const float* __restrict__ cw,
    const float* __restrict__ cb, unsigned short* __restrict__ u)
{
  const int tid = threadIdx.x;
  const int c0 = tid * 8;
  const int lt = blockIdx.x & 127;       // NL/16 tiles
  const int b  = blockIdx.x >> 7;
  const int l0 = lt * 16;

  float4 wv[8];
  #pragma unroll
  for (int j = 0; j < 8; ++j)
    wv[j] = reinterpret_cast<const float4*>(cw + (size_t)c0 * 4)[j];
  float bias[8];
  {
    float4 b0 = reinterpret_cast<const float4*>(cb + c0)[0];
    float4 b1 = reinterpret_cast<const float4*>(cb + c0)[1];
    bias[0]=b0.x; bias[1]=b0.y; bias[2]=b0.z; bias[3]=b0.w;
    bias[4]=b1.x; bias[5]=b1.y; bias[6]=b1.z; bias[7]=b1.w;
  }

  const size_t base = ((size_t)b * NL + l0) * NDI + c0;
  float w0[8], w1[8], w2[8];   // rows l0-3, l0-2, l0-1
  if (l0 >= 3) {
    int4 r0 = *reinterpret_cast<const int4*>(up + base - 3 * NDI);
    int4 r1 = *reinterpret_cast<const int4*>(up + base - 2 * NDI);
    int4 r2 = *reinterpret_cast<const int4*>(up + base - 1 * NDI);
    dec8(r0, w0); dec8(r1, w1); dec8(r2, w2);
  } else {
    #pragma unroll
    for (int j = 0; j < 8; ++j) { w0[j] = 0.f; w1[j] = 0.f; w2[j] = 0.f; }
  }

  #pragma unroll
  for (int l = 0; l < 16; ++l) {
    int4 raw = *reinterpret_cast<const int4*>(up + base + (size_t)l * NDI);
    float cur[8];
    dec8(raw, cur);
    unsigned short o[8];
    #pragma unroll
    for (int j = 0; j < 8; ++j) {
      const float a = bias[j] + wv[j].x * w0[j] + wv[j].y * w1[j]
                              + wv[j].z * w2[j] + wv[j].w * cur[j];
      o[j] = f2bf(a / (1.f + __expf(-a)));
    }
    ushort4 o0 = {o[0], o[1], o[2], o[3]};
    ushort4 o1 = {o[4], o[5], o[6], o[7]};
    unsigned short* dst = u + base + (size_t)l * NDI;
    *reinterpret_cast<ushort4*>(dst)     = o0;
    *reinterpret_cast<ushort4*>(dst + 4) = o1;
    #pragma unroll
    for (int j = 0; j < 8; ++j) { w0[j] = w1[j]; w1[j] = w2[j]; w2[j] = cur[j]; }
  }
}

// ---------------- xd projection (MFMA): u(16384x2048 bf16) @ WxT^T(96x2048) --
// 64-row tiles (grid 256 = full GPU), 4 waves, XOR-swizzled LDS (2-way free),
// double-buffered global_load_lds staging.
// cols 0..63 -> xdt bf16 [row][64]; 64..79 -> xb f32; 80..95 -> xc f32
__global__ __launch_bounds__(256) void k_xd_mfma(
    const unsigned short* __restrict__ A, const unsigned short* __restrict__ BT,
    unsigned short* __restrict__ xdt, float* __restrict__ xb,
    float* __restrict__ xc)
{
  __shared__ __align__(16) unsigned short As[2][64 * 32];
  __shared__ __align__(16) unsigned short Bs[2][96 * 32];
  const int tid = threadIdx.x, lane = tid & 63, wvv = tid >> 6;  // 4 waves
  const int m0 = blockIdx.x * 64;
  const int m16 = lane & 15, kb = lane >> 4;
  const int sw = (kb ^ ((m16 >> 1) & 3)) * 8;   // swizzled k-offset (shorts)

  f32x4 acc[6];
  #pragma unroll
  for (int j = 0; j < 6; ++j)
    #pragma unroll
    for (int r = 0; r < 4; ++r) acc[j][r] = 0.f;

  auto STG = [&](int bb, int kg) {
    {
      const int row = tid >> 2, c = tid & 3;
      const int sc = c ^ ((row >> 1) & 3);
      gld_lds16(A + (size_t)(m0 + row) * NDI + kg + sc * 8, &As[bb][tid * 8]);
      gld_lds16(BT + (size_t)row * NDI + kg + sc * 8, &Bs[bb][tid * 8]);
    }
    if (tid < 128) {
      const int s = 256 + tid;
      const int row = s >> 2, c = s & 3;
      const int sc = c ^ ((row >> 1) & 3);
      gld_lds16(BT + (size_t)row * NDI + kg + sc * 8, &Bs[bb][s * 8]);
    }
  };

  STG(0, 0);
  asm volatile("s_waitcnt vmcnt(0)" ::: "memory");
  __syncthreads();

  for (int t = 0; t < NDI / 32; ++t) {
    const int cur = t & 1;
    if (t + 1 < NDI / 32) STG(cur ^ 1, (t + 1) * 32);
    bf16x8 af = *reinterpret_cast<const bf16x8*>(&As[cur][(wvv * 16 + m16) * 32 + sw]);
    bf16x8 bfr[6];
    #pragma unroll
    for (int j = 0; j < 6; ++j)
      bfr[j] = *reinterpret_cast<const bf16x8*>(&Bs[cur][(j * 16 + m16) * 32 + sw]);
    #pragma unroll
    for (int j = 0; j < 6; ++j)
      acc[j] = __builtin_amdgcn_mfma_f32_16x16x32_bf16(af, bfr[j], acc[j], 0, 0, 0);
    asm volatile("s_waitcnt vmcnt(0)" ::: "memory");
    __syncthreads();
  }

  const int r0 = kb * 4;
  #pragma unroll
  for (int j = 0; j < 6; ++j) {
    const int col = j * 16 + m16;
    #pragma unroll
    for (int r = 0; r < 4; ++r) {
      const int row = m0 + wvv * 16 + r0 + r;
      const float v = acc[j][r];
      if (j < 4)       xdt[(size_t)row * 64 + col] = f2bf(v);
      else if (j == 4) xb[(size_t)row * 16 + col - 64] = v;
      else             xc[(size_t)row * 16 + col - 80] = v;
    }
  }
}

// ---------------- chunked selective scan, lane-per-channel ----------------
// PHASE 0: local scan -> HF[b][c][d][s] final state, Sdt[b][c][d] = sum(dt)
// PHASE 1: scan from corrected init (in HF); y = (h.C + u*D)*silu(z) over u_io
// Fast path (input-structure detected at runtime, __all-uniform): when
// Ac[s] == Ac[0]*(s+1) (A_log = log(arange(1..NDS)) broadcast), dA_s = q^(s+1)
// with q = exp(dt*Ac[0]) -> 1 exp + 15 mul instead of 16 exp.
template<int PHASE>
__global__ __launch_bounds__(256) void k_scan3(
    const unsigned short* __restrict__ dt, unsigned short* __restrict__ u_io,
    const unsigned short* __restrict__ z,
    const float* __restrict__ xb, const float* __restrict__ xc,
    const float* __restrict__ A_log, const float* __restrict__ Dp,
    float* __restrict__ HF, float* __restrict__ Sdt)
{
  const int tid = threadIdx.x;
  const int blk = blockIdx.x;
  const int b = blk >> 7;
  const int c = (blk >> 3) & (CH - 1);
  if (PHASE == 0 && c == CH - 1) return;   // last chunk's carry unused
  const int d = (blk & 7) * 256 + tid;

  __shared__ float Bsl[CL][16];
  __shared__ float Csl[(PHASE == 1) ? CL : 1][16];
  const size_t rbase = (size_t)b * NL + (size_t)c * CL;
  #pragma unroll
  for (int i = 0; i < 2; ++i) {
    const int idx = i * 256 + tid;       // 0..511  (CL*16/4 = 512 float4)
    const int r = idx >> 2, q = idx & 3;
    reinterpret_cast<float4*>(&Bsl[r][q * 4])[0] =
        reinterpret_cast<const float4*>(xb + (rbase + r) * 16)[q];
    if constexpr (PHASE == 1)
      reinterpret_cast<float4*>(&Csl[r][q * 4])[0] =
          reinterpret_cast<const float4*>(xc + (rbase + r) * 16)[q];
  }
  __syncthreads();

  float Ac[16];
  #pragma unroll
  for (int q = 0; q < 4; ++q) {
    float4 a = reinterpret_cast<const float4*>(A_log + (size_t)d * 16)[q];
    Ac[q*4+0] = -__expf(a.x); Ac[q*4+1] = -__expf(a.y);
    Ac[q*4+2] = -__expf(a.z); Ac[q*4+3] = -__expf(a.w);
  }
  bool fastok = true;
  #pragma unroll
  for (int s = 1; s < 16; ++s)
    fastok = fastok && (fabsf(Ac[s] - Ac[0] * (float)(s + 1)) <= 1e-5f * fabsf(Ac[s]));
  const bool fast = __all(fastok);

  const size_t hoff = ((size_t)(b * CH + c) * NDI + d) * 16;
  float h[16];
  if constexpr (PHASE == 0) {
    #pragma unroll
    for (int s = 0; s < 16; ++s) h[s] = 0.f;
  } else {
    #pragma unroll
    for (int q = 0; q < 4; ++q) {
      float4 hv = reinterpret_cast<const float4*>(HF + hoff)[q];
      h[q*4+0] = hv.x; h[q*4+1] = hv.y; h[q*4+2] = hv.z; h[q*4+3] = hv.w;
    }
  }
  const float Dd = Dp[d];
  const float Ac0 = Ac[0];
  float sdt = 0.f;
  size_t idx = rbase * NDI + d;

  if (fast) {
    for (int l = 0; l < CL; ++l, idx += NDI) {
      const float dtv = bf2f(dt[idx]);
      const float uv  = bf2f(u_io[idx]);
      const float dtu = dtv * uv;
      const float qq = __expf(dtv * Ac0);
      float e = qq;
      if constexpr (PHASE == 0) {
        sdt += dtv;
        #pragma unroll
        for (int s = 0; s < 16; ++s) {
          h[s] = h[s] * e + dtu * Bsl[l][s];
          e *= qq;
        }
      } else {
        float yp = 0.f;
        #pragma unroll
        for (int s = 0; s < 16; ++s) {
          h[s] = h[s] * e + dtu * Bsl[l][s];
          yp += h[s] * Csl[l][s];
          e *= qq;
        }
        const float zv = bf2f(z[idx]);
        const float sil = zv / (1.f + __expf(-zv));
        u_io[idx] = f2bf((yp + uv * Dd) * sil);
      }
    }
  } else {
    for (int l = 0; l < CL; ++l, idx += NDI) {
      const float dtv = bf2f(dt[idx]);
      const float uv  = bf2f(u_io[idx]);
      const float dtu = dtv * uv;
      if constexpr (PHASE == 0) {
        sdt += dtv;
        #pragma unroll
        for (int s = 0; s < 16; ++s) {
          const float e = __expf(dtv * Ac[s]);
          h[s] = h[s] * e + dtu * Bsl[l][s];
        }
      } else {
        float yp = 0.f;
        #pragma unroll
        for (int s = 0; s < 16; ++s) {
          const float e = __expf(dtv * Ac[s]);
          h[s] = h[s] * e + dtu * Bsl[l][s];
          yp += h[s] * Csl[l][s];
        }
        const float zv = bf2f(z[idx]);
        const float sil = zv / (1.f + __expf(-zv));
        u_io[idx] = f2bf((yp + uv * Dd) * sil);
      }
    }
  }

  if constexpr (PHASE == 0) {
    #pragma unroll
    for (int q = 0; q < 4; ++q) {
      float4 hv = {h[q*4+0], h[q*4+1], h[q*4+2], h[q*4+3]};
      reinterpret_cast<float4*>(HF + hoff)[q] = hv;
    }
    Sdt[(size_t)(b * CH + c) * NDI + d] = sdt;
  }
}

// serial combine over chunks: HF[b][c][d][s] <- init state of chunk c
__global__ __launch_bounds__(256) void k_comb(
    float* __restrict__ HF, const float* __restrict__ Sdt,
    const float* __restrict__ A_log)
{
  const int t = blockIdx.x * 256 + threadIdx.x;   // b*32768 + d*16 + s
  const int b = t >> 15;
  const int q = t & 32767;
  const int d = q >> 4;
  const float Ac = -__expf(A_log[q]);
  float H = 0.f;
  #pragma unroll
  for (int c = 0; c < CH; ++c) {
    const size_t off = (((size_t)(b * CH + c) * NDI) << 4) + q;
    const float hf = HF[off];
    const float p  = __expf(Ac * Sdt[(size_t)(b * CH + c) * NDI + d]);
    HF[off] = H;
    H = p * H + hf;
  }
}

extern "C" void kernel_launch(void* const* d_in, const int* in_sizes, int n_in,
                              void* d_out, int out_size, void* d_ws, size_t ws_size,
                              hipStream_t stream) {
  (void)in_sizes; (void)n_in; (void)out_size; (void)ws_size;
  const float* x      = (const float*)d_in[0];
  const float* ln_w   = (const float*)d_in[1];
  const float* ln_b   = (const float*)d_in[2];
  const float* W_in   = (const float*)d_in[3];
  const float* conv_w = (const float*)d_in[4];
  const float* conv_b = (const float*)d_in[5];
  const float* W_x    = (const float*)d_in[6];
  const float* W_dt   = (const float*)d_in[7];
  const float* b_dt   = (const float*)d_in[8];
  const float* A_log  = (const float*)d_in[9];
  const float* Dp     = (const float*)d_in[10];
  const float* W_out  = (const float*)d_in[11];
  float* out = (float*)d_out;

  char* ws = (char*)d_ws;
  // 0..32M: xn (bf16, dead after GEMM1) -> HF (f32, scan)
  unsigned short* xn   = (unsigned short*)(ws);
  float*          HF   = (float*)(ws);
  unsigned short* upre = (unsigned short*)(ws + 33554432);   // 64M: u-pre / dt
  unsigned short* zbuf = (unsigned short*)(ws + 100663296);  // 64M
  unsigned short* ubuf = (unsigned short*)(ws + 167772160);  // 64M: u / y
  unsigned short* xdt  = (unsigned short*)(ws + 234881024);  // 2M (dead after dt-proj) -> Sdt
  float*          Sdt  = (float*)(ws + 234881024);           // 2M
  float*          xb   = (float*)(ws + 236978176);           // 1M
  float*          xc   = (float*)(ws + 238026752);           // 1M
  unsigned short* WxT  = (unsigned short*)(ws + 239075328);  // 384K
  unsigned short* WdtT = (unsigned short*)(ws + 239468544);  // 256K
  unsigned short* WinT = (unsigned short*)(ws + 240123904);  // 8M
  unsigned short* WoutT= (unsigned short*)(ws + 248512512);  // 4M -> ends 252706816

  // weight prep
  dim3 gt1(4096 / 32, 1024 / 32);
  k_transpose<<<gt1, 256, 0, stream>>>(W_in, WinT, 1024, 4096);
  dim3 gt2(1024 / 32, 2048 / 32);
  k_transpose<<<gt2, 256, 0, stream>>>(W_out, WoutT, 2048, 1024);
  dim3 gt3(96 / 32, 2048 / 32);
  k_transpose<<<gt3, 256, 0, stream>>>(W_x, WxT, 2048, 96);
  dim3 gt4(2048 / 32, 64 / 32);
  k_transpose<<<gt4, 256, 0, stream>>>(W_dt, WdtT, 64, 2048);

  k_ln<<<NM, 256, 0, stream>>>(x, ln_w, ln_b, xn);

  // GEMM1: 16384x4096x1024, 2-phase 256^2, 2 blocks/CU
  k_mfma2<0><<<(NM / 256) * (4096 / 256), 512, 0, stream>>>(
      xn, WinT, 1024, 4096, upre, zbuf, nullptr);

  k_conv<<<NB * (NL / 16), 256, 0, stream>>>(upre, conv_w, conv_b, ubuf);

  k_xd_mfma<<<NM / 64, 256, 0, stream>>>(ubuf, WxT, xdt, xb, xc);

  dim3 g3(2048 / 128, NM / 128);
  k_mfma_dt<<<g3, 256, 0, stream>>>(xdt, WdtT, 64, upre, b_dt, 2048);

  const int nscan = NB * CH * (NDI / 256);   // 1024 blocks
  k_scan3<0><<<nscan, 256, 0, stream>>>(upre, ubuf, zbuf, xb, xc, A_log, Dp, HF, Sdt);
  k_comb<<<NB * NDI * NDS / 256, 256, 0, stream>>>(HF, Sdt, A_log);
  k_scan3<1><<<nscan, 256, 0, stream>>>(upre, ubuf, zbuf, xb, xc, A_log, Dp, HF, Sdt);

  // GEMM4: 16384x1024x2048, 2-phase 256^2, +residual
  k_mfma2<1><<<(NM / 256) * (1024 / 256), 512, 0, stream>>>(
      ubuf, WoutT, 2048, 1024, out, nullptr, x);
}